// Round 1
// baseline (383.779 us; speedup 1.0000x reference)
//
#include <hip/hip_runtime.h>
#include <math.h>

// Problem constants (from setup_inputs): x [S,C,H,W] fp32, k = stride = 2
#define S    258
#define C    64
#define L    262144              // floats per layer (C*H*W)
#define NP   65536               // windows per layer (C*32*32)
#define XOUT (S * NP)            // x_out element count

// ---------------------------------------------------------------------------
// Single fused kernel. Grid 512 = (c, hq): each block owns a contiguous
// 512-float slice (8 input rows) of channel c -> 128 output windows.
// Per thread: one float2 column pair, full-s reduction (layers 1..257) in
// registers while streaming x contiguously (float2 at 1 MiB layer stride;
// at any instant the 512 co-resident blocks cover a full 1 MiB layer densely).
// Window assembly via __shfl_xor(32) inside the wave (top row lanes 0..31,
// bottom row lanes 32..63) -- no LDS staging, no partial round-trip, no
// second kernel. Each block zeros exactly its OWN eps slice (128 floats x
// 256 layers), so the rare exact-copy overwrite is ordered by the block's
// own __syncthreads (no cross-block race).
// ---------------------------------------------------------------------------
__global__ __launch_bounds__(256) void k_fused(const float* __restrict__ x,
                                               const float* __restrict__ x_true,
                                               float* __restrict__ out) {
    __shared__ int ex_n;
    __shared__ int ex_p[128];
    __shared__ int ex_pos[128];

    const int b  = blockIdx.x;           // c*8 + hq
    const int c  = b >> 3;
    const int hq = b & 7;
    const int t  = threadIdx.x;
    if (t == 0) ex_n = 0;

    // Fire-and-forget zero of this block's eps slice: layers 1..256,
    // 128 floats (32 float4) per layer, 128 KB total. These are the only
    // eps positions this block can later exact-copy into.
    {
        const float4 z = make_float4(0.f, 0.f, 0.f, 0.f);
        float4* o4 = (float4*)out + (size_t)(c * 256 + hq * 32 + (t & 31));
        const int s0 = 1 + (t >> 5);     // 1..8
        #pragma unroll
        for (int i = 0; i < 32; ++i)
            o4[(size_t)(s0 + i * 8) * 16384] = z;   // 16384 float4 per layer
    }

    const int slice = c * 4096 + hq * 512;           // layer-local base
    const float* px = x + slice + 2 * t;

    const float2 x0 = *(const float2*)px;            // s = 0 (center layer)
    float e0 = 0.f, e1 = 0.f;
    const float* ps = px + L;
    #pragma unroll 8
    for (int s = 1; s <= 256; ++s) {                 // eps layers
        float2 v = *(const float2*)ps;
        e0 += fabsf(v.x);
        e1 += fabsf(v.y);
        ps += L;
    }
    const float2 nz = *(const float2*)ps;            // s = 257 (noise layer)
    const float n0 = fabsf(nz.x), n1 = fabsf(nz.y);
    e0 += n0;
    e1 += n1;

    __syncthreads();   // ex_n init visible; zero-stores ordered (block scope)

    // Exchange with the other window row: lane t <-> t^32 (same 64-lane wave)
    const float ox0 = __shfl_xor(x0.x, 32, 64);
    const float ox1 = __shfl_xor(x0.y, 32, 64);
    const float oe0 = __shfl_xor(e0,   32, 64);
    const float oe1 = __shfl_xor(e1,   32, 64);
    const float on0 = __shfl_xor(n0,   32, 64);
    const float on1 = __shfl_xor(n1,   32, 64);

    const int lane = t & 63;
    if (lane < 32) {
        // window element order e = kh*2 + kw, matching pool_windows
        const float xc[4] = { x0.x, x0.y, ox0, ox1 };
        const float ee[4] = { e0,   e1,   oe0, oe1 };
        const float nn[4] = { n0,   n1,   on0, on1 };
        float lo[4], hi[4];
        #pragma unroll
        for (int e = 0; e < 4; ++e) {
            lo[e] = xc[e] - ee[e];
            hi[e] = xc[e] + ee[e];
        }

        int istar = 0;   // first-max tie-break like jnp.argmax
        #pragma unroll
        for (int e = 1; e < 4; ++e) if (lo[e] > lo[istar]) istar = e;

        const float lstar = lo[istar];
        const float umax  = fmaxf(fmaxf(hi[0], hi[1]), fmaxf(hi[2], hi[3]));
        float uoth = -INFINITY;
        #pragma unroll
        for (int e = 0; e < 4; ++e) if (e != istar) uoth = fmaxf(uoth, hi[e]);

        // exact: x_max = hi[istar] == umax (u_other <= lstar <= hi[istar]);
        // box:   x_min = lstar, x_max = umax. x_min = lstar in BOTH branches.
        const bool exact = (lstar >= uoth);
        const int  wr    = t >> 6;                    // wave id = window row
        const int  top   = wr * 128 + lane * 2;       // within slice
        const int  pw    = c * 1024 + hq * 128 + wr * 32 + lane;

        float center, noise;
        if (exact) {
            center = xc[istar];
            noise  = nn[istar];
            const int i = atomicAdd(&ex_n, 1);
            ex_p[i]   = pw;
            ex_pos[i] = slice + top + (istar & 1) + (istar >> 1) * 64;
        } else {
            center = 0.5f * (lstar + umax);
            noise  = 0.5f * (umax - lstar);
        }

        out[pw] = center;                             // x_out layer 0
        out[(size_t)(S - 1) * NP + pw] = noise;       // x_out noise layer
        out[XOUT + pw] = lstar;                       // x_min
        out[XOUT + NP + pw] = umax;                   // x_max

        const float2 ta = *(const float2*)(x_true + slice + top);
        const float2 tb = *(const float2*)(x_true + slice + top + 64);
        out[XOUT + 2 * NP + pw] = fmaxf(fmaxf(ta.x, ta.y), fmaxf(tb.x, tb.y));
    }

    __syncthreads();
    // Rare exact windows: copy the winning element's affine form through
    // eps layers 1..256, one layer per thread (all in this block's own
    // zeroed slice -> ordered by the barriers above).
    const int n = ex_n;
    for (int j = 0; j < n; ++j) {
        out[(size_t)(1 + t) * NP + ex_p[j]] = x[(size_t)(1 + t) * L + ex_pos[j]];
    }
}

extern "C" void kernel_launch(void* const* d_in, const int* in_sizes, int n_in,
                              void* d_out, int out_size, void* d_ws, size_t ws_size,
                              hipStream_t stream) {
    const float* x      = (const float*)d_in[0];
    const float* x_true = (const float*)d_in[1];
    k_fused<<<C * 8, 256, 0, stream>>>(x, x_true, (float*)d_out);
}